// Round 14
// baseline (329.038 us; speedup 1.0000x reference)
//
#include <hip/hip_runtime.h>
#include <stdint.h>

// RBM CD-k fused MFMA kernel for MI355X (round 14): r13 body, (256,3) bound.
// r8/r10/r13 proved: a 128-unified budget makes the allocator clamp arch VGPRs
// to 64 and spill ~10 dwords/thread (~80 MB scratch) no matter how lean the
// body. launch_bounds' 2nd arg is only the ALLOCATOR CAP; achieved occupancy
// is min(LDS-limit, floor(512/actual_regs)). With (256,3) the cap is 170, the
// allocator allocates what it needs (r9's heavier body: 116 unified), and
// since 116 <= 128 the reg-wise occupancy stays 4 waves/SIMD; LDS 40960 B
// allows exactly 4 blocks/CU. Net: keep 16 waves/CU AND kill the spill.
// Body is r13-identical: transposed D[unit][chain] fp8 GEMMs, states 1/16
// (0x18), W tables 16*W via prep kernel, bias GEMM A=256*Wy|256*b B=lstm/16|1
// C*=1/16, peeled t=0/t=k-1, pair-hash RNG, per-lane pbits register.
// RNG statistically equivalent to jax threefry for these 262144-chain-averaged
// scalars (r1-r13: absmax <= 1.03e-2 vs threshold 1.22).

#define NV 88
#define NH 150
#define NR 100
#define NBT (128*2048)
#define CPB 32
#define NBLK (NBT/CPB)   // 8192

// byte strides (fp8 = 1 B/elem)
#define WSTR 168   // Wl  [96][168]   W row-major (visible A); 168/4=42, 2-way banks
#define TSTR 104   // WTl [152][104]  W^T (hidden A); rows 152-159 virtual (in Hl)
#define HSTR 168   // Hl  [32][168]   hidden states (visible B rows), K=160 in-row
#define VSTR 104   // Vl  [32][104]   visible states (hidden B rows), K=96 in-row
#define LSTR 136   // Ls [32][136] / Yh [160][136] / Yv [96][136]

// LDS arena (bytes)
#define OFF_WL    0        // 96*168  = 16128
#define OFF_WT    16128    // 152*104 = 15808 -> 31936
#define OFF_H     31936    // 32*168  = 5376  -> 37312
#define OFF_V     37312    // 32*104  = 3328  -> 40640
#define OFF_REDC  40640    // 32*2*4  = 256   -> 40896
#define SMEM_SZ   40896    // rounds to 40960 -> exactly 4 blocks/CU (LDS-wise)
#define OFF_LS    0        // overlay [32][136]=4352, dead before W copy

// d_ws layout: wsf partials then fp8 tables
#define WSF_BYTES (NBLK*3*4)          // 98304
#define TAB_WL    0                   // 16128
#define TAB_WT    16128               // 15808 -> 31936
#define TAB_YH    31936               // 160*136=21760 -> 53696
#define TAB_YV    53696               // 96*136=13056  -> 66752
#define TAB_BYTES 66752

typedef float f32x4 __attribute__((ext_vector_type(4)));

__device__ __forceinline__ uint32_t hashu(uint32_t x) {
  x *= 0x9E3779B9u;
  x ^= x >> 16;
  x *= 0x85EBCA6Bu;
  x ^= x >> 16;
  return x;
}

// float -> OCP e4m3fn, RNE, saturate to 448
__device__ __forceinline__ uint8_t f2e4m3(float x) {
  uint8_t s = (uint8_t)((__float_as_uint(x) >> 24) & 0x80u);
  float a = fabsf(x);
  if (!(a < 448.0f)) a = 448.0f;
  if (a < 0.015625f) {                    // subnormal: lsb 2^-9
    int mi = (int)rintf(a * 512.0f);      // 0..8 (8 -> E=1,M=0)
    return s | (uint8_t)mi;
  }
  uint32_t u = __float_as_uint(a);
  u += 0x7FFFFu + ((u >> 20) & 1u);       // RNE at mantissa bit 20
  int e = (int)(u >> 23) - 127;           // -6..8
  uint32_t mm = (u >> 20) & 7u;
  return s | (uint8_t)(((e + 7) << 3) | mm);
}

// -------- one-shot table prep: block-invariant fp8 conversions --------
__global__ void rbm_prep(const float* __restrict__ W,  const float* __restrict__ bv,
                         const float* __restrict__ bh, const float* __restrict__ Wyv,
                         const float* __restrict__ Wyh, uint8_t* __restrict__ tab)
{
  for (int i = blockIdx.x*256 + threadIdx.x; i < TAB_BYTES; i += gridDim.x*256) {
    uint8_t v = 0;
    if (i < TAB_WT) {                    // Wl [96][168] = 16*W row-major
      int r = i / WSTR, c = i - r*WSTR;
      if (r < NV && c < NH) v = f2e4m3(W[r*NH + c] * 16.0f);
    } else if (i < TAB_YH) {             // WTl [152][104] = 16*W^T
      int j = i - TAB_WT;
      int r = j / TSTR, c = j - r*TSTR;
      if (r < NH && c < NV) v = f2e4m3(W[c*NH + r] * 16.0f);
    } else if (i < TAB_YV) {             // Yh [160][136] = 256*Wyh | 256*bh
      int j = i - TAB_YH;
      int r = j / LSTR, c = j - r*LSTR;
      if (r < NH) { if (c < NR) v = f2e4m3(Wyh[r*NR + c]*256.0f);
                    else if (c == NR) v = f2e4m3(bh[r]*256.0f); }
    } else {                             // Yv [96][136] = 256*Wyv | 256*bv
      int j = i - TAB_YV;
      int r = j / LSTR, c = j - r*LSTR;
      if (r < NV) { if (c < NR) v = f2e4m3(Wyv[r*NR + c]*256.0f);
                    else if (c == NR) v = f2e4m3(bv[r]*256.0f); }
    }
    tab[i] = v;
  }
}

__global__ __launch_bounds__(256, 3) void rbm_cdk_mfma(
    const float* __restrict__ padded, const float* __restrict__ mask,
    const float* __restrict__ lstm,   const uint8_t* __restrict__ tab,
    const int*  __restrict__ kptr,    float* __restrict__ wsf)
{
  __shared__ __align__(16) unsigned char smem[SMEM_SZ];
  uint8_t*  Wl   = (uint8_t*)(smem + OFF_WL);
  uint8_t*  WTl  = (uint8_t*)(smem + OFF_WT);
  uint8_t*  Hl   = (uint8_t*)(smem + OFF_H);
  uint8_t*  Vl   = (uint8_t*)(smem + OFF_V);
  float*    redc = (float*)  (smem + OFF_REDC);  // [32][2]
  uint8_t*  Ls   = (uint8_t*)(smem + OFF_LS);

  const int tid = threadIdx.x;
  const int l   = tid & 63;
  const int w   = tid >> 6;        // 0..3
  const int nc  = w >> 1;          // chain-half (16 chains)
  const int h   = w & 1;           // unit-half
  const int Cb  = blockIdx.x * CPB;
  const int k   = kptr[0];

  const int col = l & 15;          // N-dim = chain within tile
  const int g   = l >> 4;          // K-group / C-row group
  const int kb8 = g * 8;
  const int chain = 16*nc + col;   // local chain 0..31
  const int Cg    = Cb + chain;    // global chain (< 2^18)

  // ====== Phase 1: stage Ls (fp8) + Vl + zero Hl ======
  for (int i = tid; i < CPB*LSTR; i += 256) {
    int r = i / LSTR, c = i - r*LSTR;
    uint8_t v = 0;
    if (c < NR) v = f2e4m3(lstm[(size_t)(Cb + r)*NR + c] * 0.0625f);
    else if (c == NR) v = 0x18;                     // 1/16: bias-fold "one"
    Ls[i] = v;
  }
  for (int i = tid; i < CPB*VSTR; i += 256) {
    int r = i / VSTR, c = i - r*VSTR;
    uint8_t v = 0;
    if (c < NV) v = (padded[(size_t)(Cb + r)*NV + c] > 0.5f) ? 0x18 : 0;
    Vl[i] = v;
  }
  {
    uint32_t* H32 = (uint32_t*)Hl;
    for (int i = tid; i < CPB*HSTR/4; i += 256) H32[i] = 0;
  }
  __syncthreads();

  // ====== Phase 2: bias GEMMs (transposed): A=Yh/Yv rows (global), B=Ls rows ======
  f32x4 bhF[5], bvF[3];   // D[unit][chain] fragments
  {
    const uint8_t* Yhg = tab + TAB_YH;
    const uint8_t* Yvg = tab + TAB_YV;
    long bl[4];
    #pragma unroll
    for (int ks = 0; ks < 4; ++ks)
      bl[ks] = *(const long*)(Ls + chain*LSTR + kb8 + 32*ks);
    #pragma unroll
    for (int ni = 0; ni < 5; ++ni) {
      const int n = h*5 + ni;
      f32x4 acc = {0.f, 0.f, 0.f, 0.f};
      #pragma unroll
      for (int ks = 0; ks < 4; ++ks) {
        long a = *(const long*)(Yhg + (size_t)(16*n + col)*LSTR + kb8 + 32*ks);
        acc = __builtin_amdgcn_mfma_f32_16x16x32_fp8_fp8(a, bl[ks], acc, 0, 0, 0);
      }
      #pragma unroll
      for (int r = 0; r < 4; ++r) acc[r] *= 0.0625f;
      bhF[ni] = acc;
    }
    #pragma unroll
    for (int ni = 0; ni < 3; ++ni) {
      const int n = h*3 + ni;
      f32x4 acc = {0.f, 0.f, 0.f, 0.f};
      #pragma unroll
      for (int ks = 0; ks < 4; ++ks) {
        long a = *(const long*)(Yvg + (size_t)(16*n + col)*LSTR + kb8 + 32*ks);
        acc = __builtin_amdgcn_mfma_f32_16x16x32_fp8_fp8(a, bl[ks], acc, 0, 0, 0);
      }
      #pragma unroll
      for (int r = 0; r < 4; ++r) acc[r] *= 0.0625f;
      bvF[ni] = acc;
    }
  }
  __syncthreads();   // Ls overlay dead

  // ====== Phase 3: copy W/W^T fp8 tables to LDS + padded bits -> register ======
  {
    const uint4* src = (const uint4*)tab;          // [0,31936) = Wl|WTl
    uint4* dst = (uint4*)smem;
    for (int i = tid; i < 31936/16; i += 256) dst[i] = src[i];
  }
  uint32_t pbits = 0;   // this lane's 12 visible units of `padded` (bit 4*ni+r)
  #pragma unroll
  for (int ni = 0; ni < 3; ++ni) {
    const int vb = 16*(h*3 + ni) + 4*g;
    if (vb < NV) {
      const uint32_t wd = *(const uint32_t*)(Vl + chain*VSTR + vb);
      #pragma unroll
      for (int r = 0; r < 4; ++r)
        if ((wd >> (8*r)) & 0xFFu) pbits |= 1u << (4*ni + r);
    }
  }
  __syncthreads();

  // ====== Gibbs phases (transposed layout) ======
  float spd = 0.0f, llv = 0.0f, dd = 0.0f;

  // hidden: D[j][chain] = A(W^T) x B(V^T); sample h -> packed b32 stores
  auto hidden = [&](int t, bool firstSP) {
    long bfrag[3];
    #pragma unroll
    for (int ks = 0; ks < 3; ++ks)
      bfrag[ks] = *(const long*)(Vl + chain*VSTR + kb8 + 32*ks);
    const uint32_t sbase = (uint32_t)Cg | ((uint32_t)t << 25);
    #pragma unroll
    for (int ni = 0; ni < 5; ++ni) {
      const int n = h*5 + ni;
      f32x4 acc = bhF[ni];
      #pragma unroll
      for (int ks = 0; ks < 3; ++ks) {
        long a = *(const long*)(WTl + (size_t)(16*n + col)*TSTR + kb8 + 32*ks);
        acc = __builtin_amdgcn_mfma_f32_16x16x32_fp8_fp8(a, bfrag[ks], acc, 0, 0, 0);
      }
      const int jb = 16*n + 4*g;       // this lane's 4 hidden units jb..jb+3
      const int nreal = NH - jb;       // #real among r (>=4 -> all)
      uint32_t word = 0;
      #pragma unroll
      for (int p = 0; p < 2; ++p) {
        const float pre0 = acc[2*p], pre1 = acc[2*p+1];
        const float e0 = __expf(-pre0), e1 = __expf(-pre1);
        if (firstSP) {
          if (2*p   < nreal) spd -= pre0 + __logf(1.0f + e0);
          if (2*p+1 < nreal) spd -= pre1 + __logf(1.0f + e1);
        }
        const uint32_t x = hashu(sbase + ((uint32_t)((jb >> 1) + p) << 18));
        const float u0 = (float)(x & 0xFFFFu);
        const float u1 = (float)(x >> 16);
        const bool b0 = (2*p   < nreal) && (fmaf(u0, e0, u0) < 65536.0f);
        const bool b1 = (2*p+1 < nreal) && (fmaf(u1, e1, u1) < 65536.0f);
        word |= (b0 ? 0x18u : 0u) << (16*p);
        word |= (b1 ? 0x18u : 0u) << (16*p + 8);
      }
      if (jb < NH)   // jb>=150 rows are discarded (incl. W^T virtual rows)
        *(uint32_t*)(Hl + chain*HSTR + jb) = word;
    }
  };

  // visible: D[v][chain] = A(W) x B(H^T); sample v; (ll/dot when lastLL)
  auto visible = [&](int t, bool lastLL) {
    long bfrag[5];
    #pragma unroll
    for (int ks = 0; ks < 5; ++ks)
      bfrag[ks] = *(const long*)(Hl + chain*HSTR + kb8 + 32*ks);
    const uint32_t sbase = (uint32_t)Cg | ((uint32_t)t << 25) | (1u << 28);
    #pragma unroll
    for (int ni = 0; ni < 3; ++ni) {
      const int n = h*3 + ni;
      f32x4 acc = bvF[ni];
      #pragma unroll
      for (int ks = 0; ks < 5; ++ks) {
        long a = *(const long*)(Wl + (size_t)(16*n + col)*WSTR + kb8 + 32*ks);
        acc = __builtin_amdgcn_mfma_f32_16x16x32_fp8_fp8(a, bfrag[ks], acc, 0, 0, 0);
      }
      const int vb = 16*n + 4*g;       // this lane's 4 visible units
      const bool real = (vb < NV);     // 4-aligned: all-or-none real
      uint32_t word = 0;
      #pragma unroll
      for (int p = 0; p < 2; ++p) {
        const float pre0 = acc[2*p], pre1 = acc[2*p+1];
        const float e0 = __expf(-pre0), e1 = __expf(-pre1);
        const uint32_t x = hashu(sbase + ((uint32_t)((vb >> 1) + p) << 18));
        const float u0 = (float)(x & 0xFFFFu);
        const float u1 = (float)(x >> 16);
        const bool b0 = real && (fmaf(u0, e0, u0) < 65536.0f);
        const bool b1 = real && (fmaf(u1, e1, u1) < 65536.0f);
        if (lastLL && real) {
          const float L0 = __logf(1.0f + e0), L1 = __logf(1.0f + e1);
          const uint32_t pb0 = (pbits >> (4*ni + 2*p))     & 1u;
          const uint32_t pb1 = (pbits >> (4*ni + 2*p + 1)) & 1u;
          llv += -L0 - (pb0 ? 0.0f : pre0);
          llv += -L1 - (pb1 ? 0.0f : pre1);
          const float bvt0 = bvF[ni][2*p], bvt1 = bvF[ni][2*p+1];
          dd += (b0 ? bvt0 : 0.0f) - (pb0 ? bvt0 : 0.0f);
          dd += (b1 ? bvt1 : 0.0f) - (pb1 ? bvt1 : 0.0f);
        }
        word |= (b0 ? 0x18u : 0u) << (16*p);
        word |= (b1 ? 0x18u : 0u) << (16*p + 8);
      }
      if (real)
        *(uint32_t*)(Vl + chain*VSTR + vb) = word;
    }
  };

  // final hidden GEMM on v_sample: softplus only (no RNG / stores)
  auto finalsp = [&]() {
    long bfrag[3];
    #pragma unroll
    for (int ks = 0; ks < 3; ++ks)
      bfrag[ks] = *(const long*)(Vl + chain*VSTR + kb8 + 32*ks);
    #pragma unroll
    for (int ni = 0; ni < 5; ++ni) {
      const int n = h*5 + ni;
      f32x4 acc = bhF[ni];
      #pragma unroll
      for (int ks = 0; ks < 3; ++ks) {
        long a = *(const long*)(WTl + (size_t)(16*n + col)*TSTR + kb8 + 32*ks);
        acc = __builtin_amdgcn_mfma_f32_16x16x32_fp8_fp8(a, bfrag[ks], acc, 0, 0, 0);
      }
      const int jb = 16*n + 4*g;
      const int nreal = NH - jb;
      #pragma unroll
      for (int r = 0; r < 4; ++r) {
        if (r < nreal) {
          const float e = __expf(-acc[r]);
          spd += acc[r] + __logf(1.0f + e);
        }
      }
    }
  };

  // ====== Gibbs chain: peeled first/last ======
  hidden(0, true);                 // also accumulates -softplus(pre_padded)
  __syncthreads();
  for (int t = 0; t < k - 1; ++t) {
    visible(t, false);
    __syncthreads();
    hidden(t + 1, false);
    __syncthreads();
  }
  visible(k - 1, true);            // ll + dot terms
  __syncthreads();
  finalsp();                       // +softplus(pre_vsample)

  // ====== reduction (per-chain, lane-local scalars) ======
  float ca = dd + spd;             // cost contribution of this lane's units
  ca  += __shfl_xor(ca, 16);  ca  += __shfl_xor(ca, 32);
  llv += __shfl_xor(llv, 16); llv += __shfl_xor(llv, 32);
  if (l < 16 && h == 0) { redc[chain*2] = ca; redc[chain*2+1] = llv; }
  __syncthreads();
  if (l < 16 && h == 1) { redc[chain*2] += ca; redc[chain*2+1] += llv; }
  __syncthreads();
  if (tid < CPB) {
    const float mk = mask[Cb + tid];
    float aa = redc[tid*2]   * mk;
    float bb = redc[tid*2+1] * mk;
    float mm = mk;
    #pragma unroll
    for (int off = 1; off <= 16; off <<= 1) {
      aa += __shfl_xor(aa, off);
      bb += __shfl_xor(bb, off);
      mm += __shfl_xor(mm, off);
    }
    if (tid == 0) {
      wsf[(size_t)blockIdx.x*3+0] = aa;
      wsf[(size_t)blockIdx.x*3+1] = bb;
      wsf[(size_t)blockIdx.x*3+2] = mm;
    }
  }
}

__global__ void rbm_finalize_kernel(const float* __restrict__ wsf, float* __restrict__ out)
{
  __shared__ double sh[3][4];
  const int tid = threadIdx.x, lane = tid & 63, w = tid >> 6;
  double sa = 0.0, sb = 0.0, sm = 0.0;
  for (int i = tid; i < NBLK; i += 256) {
    sa += (double)wsf[(size_t)3*i+0];
    sb += (double)wsf[(size_t)3*i+1];
    sm += (double)wsf[(size_t)3*i+2];
  }
  #pragma unroll
  for (int off = 32; off >= 1; off >>= 1) {
    sa += __shfl_down(sa, off);
    sb += __shfl_down(sb, off);
    sm += __shfl_down(sm, off);
  }
  if (lane == 0) { sh[0][w] = sa; sh[1][w] = sb; sh[2][w] = sm; }
  __syncthreads();
  if (tid == 0) {
    double A = sh[0][0]+sh[0][1]+sh[0][2]+sh[0][3];
    double B = sh[1][0]+sh[1][1]+sh[1][2]+sh[1][3];
    double M = sh[2][0]+sh[2][1]+sh[2][2]+sh[2][3];
    out[0] = (float)(A / M);   // cost
    out[1] = (float)(B / M);   // monitor
  }
}

extern "C" void kernel_launch(void* const* d_in, const int* in_sizes, int n_in,
                              void* d_out, int out_size, void* d_ws, size_t ws_size,
                              hipStream_t stream) {
  const float* padded = (const float*)d_in[0];
  const float* mask   = (const float*)d_in[1];
  const float* lstm   = (const float*)d_in[2];
  const float* W      = (const float*)d_in[3];
  const float* bv     = (const float*)d_in[4];
  const float* bh     = (const float*)d_in[5];
  const float* Wyv    = (const float*)d_in[6];
  const float* Wyh    = (const float*)d_in[7];
  const int*   kp     = (const int*)d_in[8];
  float*   wsf = (float*)d_ws;
  uint8_t* tab = (uint8_t*)d_ws + WSF_BYTES;
  float*   out = (float*)d_out;

  rbm_prep<<<264, 256, 0, stream>>>(W, bv, bh, Wyv, Wyh, tab);
  rbm_cdk_mfma<<<NBLK, 256, 0, stream>>>(padded, mask, lstm, tab, kp, wsf);
  rbm_finalize_kernel<<<1, 256, 0, stream>>>(wsf, out);
}

// Round 15
// 291.257 us; speedup vs baseline: 1.1297x; 1.1297x over previous
//
#include <hip/hip_runtime.h>
#include <stdint.h>

// RBM CD-k fused MFMA kernel for MI355X (round 15): r13 config + pinned schedule.
// r13 vs r14 isolated the real knob: the register ALLOCATOR spends whatever
// budget it gets on scheduler ILP (pre-loading all 15 A-frags per GEMM phase,
// ~30 regs + 8 parallel exp chains). Budget 128 -> clamp arch 64 -> spill 81MB
// (r13, 360us); budget 170 -> 144 unified -> 3 waves/SIMD (r14, 403us).
// Fix: (256,4) for the guaranteed 4 waves/SIMD reg budget AND
// __builtin_amdgcn_sched_barrier(0) after every unrolled ni GEMM step to cap
// the live window at ~one GEMM's operands -> arch live ~50 <= 64 -> no spill.
// ds_read->MFMA latency per step is covered by 16 waves/CU TLP.
// Body otherwise r13/r14-identical: transposed D[unit][chain] fp8 GEMMs,
// states 1/16 (0x18), W tables 16*W via prep kernel, bias GEMM A=256*Wy|256*b
// B=lstm/16|1 C*=1/16, peeled t=0/t=k-1, pair-hash RNG, per-lane pbits.
// RNG statistically equivalent to jax threefry for these 262144-chain-averaged
// scalars (r1-r14: absmax <= 1.03e-2 vs threshold 1.22).

#define NV 88
#define NH 150
#define NR 100
#define NBT (128*2048)
#define CPB 32
#define NBLK (NBT/CPB)   // 8192

// byte strides (fp8 = 1 B/elem)
#define WSTR 168   // Wl  [96][168]   W row-major (visible A); 168/4=42, 2-way banks
#define TSTR 104   // WTl [152][104]  W^T (hidden A); rows 152-159 virtual (in Hl)
#define HSTR 168   // Hl  [32][168]   hidden states (visible B rows), K=160 in-row
#define VSTR 104   // Vl  [32][104]   visible states (hidden B rows), K=96 in-row
#define LSTR 136   // Ls [32][136] / Yh [160][136] / Yv [96][136]

// LDS arena (bytes)
#define OFF_WL    0        // 96*168  = 16128
#define OFF_WT    16128    // 152*104 = 15808 -> 31936
#define OFF_H     31936    // 32*168  = 5376  -> 37312
#define OFF_V     37312    // 32*104  = 3328  -> 40640
#define OFF_REDC  40640    // 32*2*4  = 256   -> 40896
#define SMEM_SZ   40896    // rounds to 40960 -> exactly 4 blocks/CU (LDS-wise)
#define OFF_LS    0        // overlay [32][136]=4352, dead before W copy

// d_ws layout: wsf partials then fp8 tables
#define WSF_BYTES (NBLK*3*4)          // 98304
#define TAB_WL    0                   // 16128
#define TAB_WT    16128               // 15808 -> 31936
#define TAB_YH    31936               // 160*136=21760 -> 53696
#define TAB_YV    53696               // 96*136=13056  -> 66752
#define TAB_BYTES 66752

typedef float f32x4 __attribute__((ext_vector_type(4)));

#define SCHED_FENCE() __builtin_amdgcn_sched_barrier(0)

__device__ __forceinline__ uint32_t hashu(uint32_t x) {
  x *= 0x9E3779B9u;
  x ^= x >> 16;
  x *= 0x85EBCA6Bu;
  x ^= x >> 16;
  return x;
}

// float -> OCP e4m3fn, RNE, saturate to 448
__device__ __forceinline__ uint8_t f2e4m3(float x) {
  uint8_t s = (uint8_t)((__float_as_uint(x) >> 24) & 0x80u);
  float a = fabsf(x);
  if (!(a < 448.0f)) a = 448.0f;
  if (a < 0.015625f) {                    // subnormal: lsb 2^-9
    int mi = (int)rintf(a * 512.0f);      // 0..8 (8 -> E=1,M=0)
    return s | (uint8_t)mi;
  }
  uint32_t u = __float_as_uint(a);
  u += 0x7FFFFu + ((u >> 20) & 1u);       // RNE at mantissa bit 20
  int e = (int)(u >> 23) - 127;           // -6..8
  uint32_t mm = (u >> 20) & 7u;
  return s | (uint8_t)(((e + 7) << 3) | mm);
}

// -------- one-shot table prep: block-invariant fp8 conversions --------
__global__ void rbm_prep(const float* __restrict__ W,  const float* __restrict__ bv,
                         const float* __restrict__ bh, const float* __restrict__ Wyv,
                         const float* __restrict__ Wyh, uint8_t* __restrict__ tab)
{
  for (int i = blockIdx.x*256 + threadIdx.x; i < TAB_BYTES; i += gridDim.x*256) {
    uint8_t v = 0;
    if (i < TAB_WT) {                    // Wl [96][168] = 16*W row-major
      int r = i / WSTR, c = i - r*WSTR;
      if (r < NV && c < NH) v = f2e4m3(W[r*NH + c] * 16.0f);
    } else if (i < TAB_YH) {             // WTl [152][104] = 16*W^T
      int j = i - TAB_WT;
      int r = j / TSTR, c = j - r*TSTR;
      if (r < NH && c < NV) v = f2e4m3(W[c*NH + r] * 16.0f);
    } else if (i < TAB_YV) {             // Yh [160][136] = 256*Wyh | 256*bh
      int j = i - TAB_YH;
      int r = j / LSTR, c = j - r*LSTR;
      if (r < NH) { if (c < NR) v = f2e4m3(Wyh[r*NR + c]*256.0f);
                    else if (c == NR) v = f2e4m3(bh[r]*256.0f); }
    } else {                             // Yv [96][136] = 256*Wyv | 256*bv
      int j = i - TAB_YV;
      int r = j / LSTR, c = j - r*LSTR;
      if (r < NV) { if (c < NR) v = f2e4m3(Wyv[r*NR + c]*256.0f);
                    else if (c == NR) v = f2e4m3(bv[r]*256.0f); }
    }
    tab[i] = v;
  }
}

__global__ __launch_bounds__(256, 4) void rbm_cdk_mfma(
    const float* __restrict__ padded, const float* __restrict__ mask,
    const float* __restrict__ lstm,   const uint8_t* __restrict__ tab,
    const int*  __restrict__ kptr,    float* __restrict__ wsf)
{
  __shared__ __align__(16) unsigned char smem[SMEM_SZ];
  uint8_t*  Wl   = (uint8_t*)(smem + OFF_WL);
  uint8_t*  WTl  = (uint8_t*)(smem + OFF_WT);
  uint8_t*  Hl   = (uint8_t*)(smem + OFF_H);
  uint8_t*  Vl   = (uint8_t*)(smem + OFF_V);
  float*    redc = (float*)  (smem + OFF_REDC);  // [32][2]
  uint8_t*  Ls   = (uint8_t*)(smem + OFF_LS);

  const int tid = threadIdx.x;
  const int l   = tid & 63;
  const int w   = tid >> 6;        // 0..3
  const int nc  = w >> 1;          // chain-half (16 chains)
  const int h   = w & 1;           // unit-half
  const int Cb  = blockIdx.x * CPB;
  const int k   = kptr[0];

  const int col = l & 15;          // N-dim = chain within tile
  const int g   = l >> 4;          // K-group / C-row group
  const int kb8 = g * 8;
  const int chain = 16*nc + col;   // local chain 0..31
  const int Cg    = Cb + chain;    // global chain (< 2^18)

  // ====== Phase 1: stage Ls (fp8) + Vl + zero Hl ======
  for (int i = tid; i < CPB*LSTR; i += 256) {
    int r = i / LSTR, c = i - r*LSTR;
    uint8_t v = 0;
    if (c < NR) v = f2e4m3(lstm[(size_t)(Cb + r)*NR + c] * 0.0625f);
    else if (c == NR) v = 0x18;                     // 1/16: bias-fold "one"
    Ls[i] = v;
  }
  for (int i = tid; i < CPB*VSTR; i += 256) {
    int r = i / VSTR, c = i - r*VSTR;
    uint8_t v = 0;
    if (c < NV) v = (padded[(size_t)(Cb + r)*NV + c] > 0.5f) ? 0x18 : 0;
    Vl[i] = v;
  }
  {
    uint32_t* H32 = (uint32_t*)Hl;
    for (int i = tid; i < CPB*HSTR/4; i += 256) H32[i] = 0;
  }
  __syncthreads();

  // ====== Phase 2: bias GEMMs (transposed): A=Yh/Yv rows (global), B=Ls rows ======
  f32x4 bhF[5], bvF[3];   // D[unit][chain] fragments
  {
    const uint8_t* Yhg = tab + TAB_YH;
    const uint8_t* Yvg = tab + TAB_YV;
    long bl[4];
    #pragma unroll
    for (int ks = 0; ks < 4; ++ks)
      bl[ks] = *(const long*)(Ls + chain*LSTR + kb8 + 32*ks);
    #pragma unroll
    for (int ni = 0; ni < 5; ++ni) {
      const int n = h*5 + ni;
      f32x4 acc = {0.f, 0.f, 0.f, 0.f};
      #pragma unroll
      for (int ks = 0; ks < 4; ++ks) {
        long a = *(const long*)(Yhg + (size_t)(16*n + col)*LSTR + kb8 + 32*ks);
        acc = __builtin_amdgcn_mfma_f32_16x16x32_fp8_fp8(a, bl[ks], acc, 0, 0, 0);
      }
      #pragma unroll
      for (int r = 0; r < 4; ++r) acc[r] *= 0.0625f;
      bhF[ni] = acc;
      SCHED_FENCE();
    }
    #pragma unroll
    for (int ni = 0; ni < 3; ++ni) {
      const int n = h*3 + ni;
      f32x4 acc = {0.f, 0.f, 0.f, 0.f};
      #pragma unroll
      for (int ks = 0; ks < 4; ++ks) {
        long a = *(const long*)(Yvg + (size_t)(16*n + col)*LSTR + kb8 + 32*ks);
        acc = __builtin_amdgcn_mfma_f32_16x16x32_fp8_fp8(a, bl[ks], acc, 0, 0, 0);
      }
      #pragma unroll
      for (int r = 0; r < 4; ++r) acc[r] *= 0.0625f;
      bvF[ni] = acc;
      SCHED_FENCE();
    }
  }
  __syncthreads();   // Ls overlay dead

  // ====== Phase 3: copy W/W^T fp8 tables to LDS + padded bits -> register ======
  {
    const uint4* src = (const uint4*)tab;          // [0,31936) = Wl|WTl
    uint4* dst = (uint4*)smem;
    for (int i = tid; i < 31936/16; i += 256) dst[i] = src[i];
  }
  uint32_t pbits = 0;   // this lane's 12 visible units of `padded` (bit 4*ni+r)
  #pragma unroll
  for (int ni = 0; ni < 3; ++ni) {
    const int vb = 16*(h*3 + ni) + 4*g;
    if (vb < NV) {
      const uint32_t wd = *(const uint32_t*)(Vl + chain*VSTR + vb);
      #pragma unroll
      for (int r = 0; r < 4; ++r)
        if ((wd >> (8*r)) & 0xFFu) pbits |= 1u << (4*ni + r);
    }
  }
  __syncthreads();

  // ====== Gibbs phases (transposed layout) ======
  float spd = 0.0f, llv = 0.0f, dd = 0.0f;

  // hidden: D[j][chain] = A(W^T) x B(V^T); sample h -> packed b32 stores
  auto hidden = [&](int t, bool firstSP) {
    long bfrag[3];
    #pragma unroll
    for (int ks = 0; ks < 3; ++ks)
      bfrag[ks] = *(const long*)(Vl + chain*VSTR + kb8 + 32*ks);
    const uint32_t sbase = (uint32_t)Cg | ((uint32_t)t << 25);
    #pragma unroll
    for (int ni = 0; ni < 5; ++ni) {
      const int n = h*5 + ni;
      f32x4 acc = bhF[ni];
      #pragma unroll
      for (int ks = 0; ks < 3; ++ks) {
        long a = *(const long*)(WTl + (size_t)(16*n + col)*TSTR + kb8 + 32*ks);
        acc = __builtin_amdgcn_mfma_f32_16x16x32_fp8_fp8(a, bfrag[ks], acc, 0, 0, 0);
      }
      const int jb = 16*n + 4*g;       // this lane's 4 hidden units jb..jb+3
      const int nreal = NH - jb;       // #real among r (>=4 -> all)
      uint32_t word = 0;
      #pragma unroll
      for (int p = 0; p < 2; ++p) {
        const float pre0 = acc[2*p], pre1 = acc[2*p+1];
        const float e0 = __expf(-pre0), e1 = __expf(-pre1);
        if (firstSP) {
          if (2*p   < nreal) spd -= pre0 + __logf(1.0f + e0);
          if (2*p+1 < nreal) spd -= pre1 + __logf(1.0f + e1);
        }
        const uint32_t x = hashu(sbase + ((uint32_t)((jb >> 1) + p) << 18));
        const float u0 = (float)(x & 0xFFFFu);
        const float u1 = (float)(x >> 16);
        const bool b0 = (2*p   < nreal) && (fmaf(u0, e0, u0) < 65536.0f);
        const bool b1 = (2*p+1 < nreal) && (fmaf(u1, e1, u1) < 65536.0f);
        word |= (b0 ? 0x18u : 0u) << (16*p);
        word |= (b1 ? 0x18u : 0u) << (16*p + 8);
      }
      if (jb < NH)   // jb>=150 rows are discarded (incl. W^T virtual rows)
        *(uint32_t*)(Hl + chain*HSTR + jb) = word;
      SCHED_FENCE();
    }
  };

  // visible: D[v][chain] = A(W) x B(H^T); sample v; (ll/dot when lastLL)
  auto visible = [&](int t, bool lastLL) {
    long bfrag[5];
    #pragma unroll
    for (int ks = 0; ks < 5; ++ks)
      bfrag[ks] = *(const long*)(Hl + chain*HSTR + kb8 + 32*ks);
    const uint32_t sbase = (uint32_t)Cg | ((uint32_t)t << 25) | (1u << 28);
    #pragma unroll
    for (int ni = 0; ni < 3; ++ni) {
      const int n = h*3 + ni;
      f32x4 acc = bvF[ni];
      #pragma unroll
      for (int ks = 0; ks < 5; ++ks) {
        long a = *(const long*)(Wl + (size_t)(16*n + col)*WSTR + kb8 + 32*ks);
        acc = __builtin_amdgcn_mfma_f32_16x16x32_fp8_fp8(a, bfrag[ks], acc, 0, 0, 0);
      }
      const int vb = 16*n + 4*g;       // this lane's 4 visible units
      const bool real = (vb < NV);     // 4-aligned: all-or-none real
      uint32_t word = 0;
      #pragma unroll
      for (int p = 0; p < 2; ++p) {
        const float pre0 = acc[2*p], pre1 = acc[2*p+1];
        const float e0 = __expf(-pre0), e1 = __expf(-pre1);
        const uint32_t x = hashu(sbase + ((uint32_t)((vb >> 1) + p) << 18));
        const float u0 = (float)(x & 0xFFFFu);
        const float u1 = (float)(x >> 16);
        const bool b0 = real && (fmaf(u0, e0, u0) < 65536.0f);
        const bool b1 = real && (fmaf(u1, e1, u1) < 65536.0f);
        if (lastLL && real) {
          const float L0 = __logf(1.0f + e0), L1 = __logf(1.0f + e1);
          const uint32_t pb0 = (pbits >> (4*ni + 2*p))     & 1u;
          const uint32_t pb1 = (pbits >> (4*ni + 2*p + 1)) & 1u;
          llv += -L0 - (pb0 ? 0.0f : pre0);
          llv += -L1 - (pb1 ? 0.0f : pre1);
          const float bvt0 = bvF[ni][2*p], bvt1 = bvF[ni][2*p+1];
          dd += (b0 ? bvt0 : 0.0f) - (pb0 ? bvt0 : 0.0f);
          dd += (b1 ? bvt1 : 0.0f) - (pb1 ? bvt1 : 0.0f);
        }
        word |= (b0 ? 0x18u : 0u) << (16*p);
        word |= (b1 ? 0x18u : 0u) << (16*p + 8);
      }
      if (real)
        *(uint32_t*)(Vl + chain*VSTR + vb) = word;
      SCHED_FENCE();
    }
  };

  // final hidden GEMM on v_sample: softplus only (no RNG / stores)
  auto finalsp = [&]() {
    long bfrag[3];
    #pragma unroll
    for (int ks = 0; ks < 3; ++ks)
      bfrag[ks] = *(const long*)(Vl + chain*VSTR + kb8 + 32*ks);
    #pragma unroll
    for (int ni = 0; ni < 5; ++ni) {
      const int n = h*5 + ni;
      f32x4 acc = bhF[ni];
      #pragma unroll
      for (int ks = 0; ks < 3; ++ks) {
        long a = *(const long*)(WTl + (size_t)(16*n + col)*TSTR + kb8 + 32*ks);
        acc = __builtin_amdgcn_mfma_f32_16x16x32_fp8_fp8(a, bfrag[ks], acc, 0, 0, 0);
      }
      const int jb = 16*n + 4*g;
      const int nreal = NH - jb;
      #pragma unroll
      for (int r = 0; r < 4; ++r) {
        if (r < nreal) {
          const float e = __expf(-acc[r]);
          spd += acc[r] + __logf(1.0f + e);
        }
      }
      SCHED_FENCE();
    }
  };

  // ====== Gibbs chain: peeled first/last ======
  hidden(0, true);                 // also accumulates -softplus(pre_padded)
  __syncthreads();
  for (int t = 0; t < k - 1; ++t) {
    visible(t, false);
    __syncthreads();
    hidden(t + 1, false);
    __syncthreads();
  }
  visible(k - 1, true);            // ll + dot terms
  __syncthreads();
  finalsp();                       // +softplus(pre_vsample)

  // ====== reduction (per-chain, lane-local scalars) ======
  float ca = dd + spd;             // cost contribution of this lane's units
  ca  += __shfl_xor(ca, 16);  ca  += __shfl_xor(ca, 32);
  llv += __shfl_xor(llv, 16); llv += __shfl_xor(llv, 32);
  if (l < 16 && h == 0) { redc[chain*2] = ca; redc[chain*2+1] = llv; }
  __syncthreads();
  if (l < 16 && h == 1) { redc[chain*2] += ca; redc[chain*2+1] += llv; }
  __syncthreads();
  if (tid < CPB) {
    const float mk = mask[Cb + tid];
    float aa = redc[tid*2]   * mk;
    float bb = redc[tid*2+1] * mk;
    float mm = mk;
    #pragma unroll
    for (int off = 1; off <= 16; off <<= 1) {
      aa += __shfl_xor(aa, off);
      bb += __shfl_xor(bb, off);
      mm += __shfl_xor(mm, off);
    }
    if (tid == 0) {
      wsf[(size_t)blockIdx.x*3+0] = aa;
      wsf[(size_t)blockIdx.x*3+1] = bb;
      wsf[(size_t)blockIdx.x*3+2] = mm;
    }
  }
}

__global__ void rbm_finalize_kernel(const float* __restrict__ wsf, float* __restrict__ out)
{
  __shared__ double sh[3][4];
  const int tid = threadIdx.x, lane = tid & 63, w = tid >> 6;
  double sa = 0.0, sb = 0.0, sm = 0.0;
  for (int i = tid; i < NBLK; i += 256) {
    sa += (double)wsf[(size_t)3*i+0];
    sb += (double)wsf[(size_t)3*i+1];
    sm += (double)wsf[(size_t)3*i+2];
  }
  #pragma unroll
  for (int off = 32; off >= 1; off >>= 1) {
    sa += __shfl_down(sa, off);
    sb += __shfl_down(sb, off);
    sm += __shfl_down(sm, off);
  }
  if (lane == 0) { sh[0][w] = sa; sh[1][w] = sb; sh[2][w] = sm; }
  __syncthreads();
  if (tid == 0) {
    double A = sh[0][0]+sh[0][1]+sh[0][2]+sh[0][3];
    double B = sh[1][0]+sh[1][1]+sh[1][2]+sh[1][3];
    double M = sh[2][0]+sh[2][1]+sh[2][2]+sh[2][3];
    out[0] = (float)(A / M);   // cost
    out[1] = (float)(B / M);   // monitor
  }
}

extern "C" void kernel_launch(void* const* d_in, const int* in_sizes, int n_in,
                              void* d_out, int out_size, void* d_ws, size_t ws_size,
                              hipStream_t stream) {
  const float* padded = (const float*)d_in[0];
  const float* mask   = (const float*)d_in[1];
  const float* lstm   = (const float*)d_in[2];
  const float* W      = (const float*)d_in[3];
  const float* bv     = (const float*)d_in[4];
  const float* bh     = (const float*)d_in[5];
  const float* Wyv    = (const float*)d_in[6];
  const float* Wyh    = (const float*)d_in[7];
  const int*   kp     = (const int*)d_in[8];
  float*   wsf = (float*)d_ws;
  uint8_t* tab = (uint8_t*)d_ws + WSF_BYTES;
  float*   out = (float*)d_out;

  rbm_prep<<<264, 256, 0, stream>>>(W, bv, bh, Wyv, Wyh, tab);
  rbm_cdk_mfma<<<NBLK, 256, 0, stream>>>(padded, mask, lstm, tab, kp, wsf);
  rbm_finalize_kernel<<<1, 256, 0, stream>>>(wsf, out);
}